// Round 10
// baseline (299.363 us; speedup 1.0000x reference)
//
#include <hip/hip_runtime.h>
#include <stdint.h>

#define NHEADS 16
#define HDIM   64
#define SEQ    2048
#define BATCH  4
#define DM     1024
#define MTOT   (BATCH*SEQ)   // 8192
#define SCALE  0.125f
#define QSCALE 0.18033688011112042f   // SCALE * log2(e)

typedef unsigned short u16;
typedef __attribute__((ext_vector_type(8))) short short8;    // 8 bf16 (4 VGPRs)
typedef __attribute__((ext_vector_type(4))) float f32x4;     // 16x16 MFMA acc
typedef __attribute__((ext_vector_type(16))) float f32x16;   // 32x32 MFMA acc
typedef __attribute__((ext_vector_type(4))) unsigned int u32x4;

__device__ __forceinline__ u16 f2bf(float f) {
  uint32_t u = __builtin_bit_cast(uint32_t, f);
  u += 0x7FFFu + ((u >> 16) & 1u);    // RNE
  return (u16)(u >> 16);
}

// raw v_exp_f32 (2^x): ~1 instr vs __ocml_exp2_f32's fixup sequence
__device__ __forceinline__ float fexp2(float x) {
#if __has_builtin(__builtin_amdgcn_exp2f)
  return __builtin_amdgcn_exp2f(x);
#else
  float r; asm("v_exp_f32 %0, %1\n\ts_nop 1" : "=v"(r) : "v"(x)); return r;
#endif
}

__device__ __forceinline__ f32x4 mfma16(short8 a, short8 b, f32x4 c) {
  return __builtin_amdgcn_mfma_f32_16x16x32_bf16(a, b, c, 0, 0, 0);
}
__device__ __forceinline__ f32x16 mfma32(short8 a, short8 b, f32x16 c) {
  return __builtin_amdgcn_mfma_f32_32x32x16_bf16(a, b, c, 0, 0, 0);
}

// async global->LDS DMA, 16B/lane; LDS dest is wave-uniform base + lane*16
__device__ __forceinline__ void gload16(const u16* g, u16* l) {
  __builtin_amdgcn_global_load_lds((const __attribute__((address_space(1))) void*)g,
                                   (__attribute__((address_space(3))) void*)l,
                                   16, 0, 0);
}

// XOR-swizzled LDS addressing (attn): linear 128-byte rows, 16B-slot swizzle (T2).
#define LDSP(base, row, boff) \
  ((u16*)((char*)(base) + (((row) << 7) + ((boff) ^ (((row) & 7) << 4)))))

__device__ __forceinline__ void hardbar() {
  __builtin_amdgcn_sched_barrier(0);
  __builtin_amdgcn_s_barrier();
  __builtin_amdgcn_sched_barrier(0);
}

// ---------------- query fp32 -> bf16 ----------------
__global__ __launch_bounds__(256) void k_conv(const float* __restrict__ in, u16* __restrict__ out) {
  size_t i = (size_t)blockIdx.x * 256 + threadIdx.x;   // one thread = 8 floats
  const float4* p = (const float4*)(in + i * 8);
  float4 a = p[0], b = p[1];
  u16 r[8] = {f2bf(a.x), f2bf(a.y), f2bf(a.z), f2bf(a.w),
              f2bf(b.x), f2bf(b.y), f2bf(b.z), f2bf(b.w)};
  *(short8*)(out + i * 8) = *(const short8*)r;
}

// ---------------- W[k][n] fp32 -> Wt[n][k] bf16 (tiled transpose) ----------------
__global__ __launch_bounds__(256) void k_convw(const float* __restrict__ w0, const float* __restrict__ w1,
                                               const float* __restrict__ w2, const float* __restrict__ w3,
                                               u16* __restrict__ o0, u16* __restrict__ o1,
                                               u16* __restrict__ o2, u16* __restrict__ o3) {
  const float* W = blockIdx.z==0?w0: blockIdx.z==1?w1: blockIdx.z==2?w2:w3;
  u16* O        = blockIdx.z==0?o0: blockIdx.z==1?o1: blockIdx.z==2?o2:o3;
  __shared__ float tile[32][33];
  int t = threadIdx.x;
  int k0 = blockIdx.y*32, n0 = blockIdx.x*32;
  int r = t >> 5, c = t & 31;
  #pragma unroll
  for (int p = 0; p < 4; ++p) tile[r + 8*p][c] = W[(size_t)(k0 + r + 8*p)*DM + n0 + c];
  __syncthreads();
  #pragma unroll
  for (int p = 0; p < 4; ++p) O[(size_t)(n0 + r + 8*p)*DM + k0 + c] = f2bf(tile[c][r + 8*p]);
}

// ---------------- GEMM v2: 256x256 tile, BK=64, 8 waves, 8-phase counted-vmcnt ----
// T2 swizzle (slot ^= row&7, via pre-swizzled global source + swizzled reads),
// T3+T4 (8 phases, vmcnt(4) only at phases 4/8), T5 (setprio around MFMA).
// Buffers: even K-tiles -> buf0, odd -> buf1. Staging schedule (iter i):
//   ph1: A-h0(2i+1)->A1  ph2: A-h1(2i+1)->A1   (A1 last read iter i-1 ph5-8)
//   ph3: B-h0(2i+2)->B0  ph4: B-h1(2i+2)->B0   (B0 reads done ph1; held in regs)
//   ph5: A-h0(2i+2)->A0  ph6: A-h1(2i+2)->A0   (A0 reads done ph4)
//   ph7: B-h0(2i+3)->B1  ph8: B-h1(2i+3)->B1   (B1 reads done ph5)
// vmcnt(4) @ph4: lands B(2i+1),A(2i+1) -> buf1 complete for ph5.
// vmcnt(4) @ph8: lands B(2i+2),A(2i+2) -> buf0 complete for next ph1.
// MODE 0: fused QKV, Wt=[3072][1024], z=n0>>10; MODE 1: fp32 out.
template<int MODE>
__global__ __launch_bounds__(512, 2) void k_gemm8(
    const u16* __restrict__ A, const u16* __restrict__ Wt,
    const float* __restrict__ bQ, const float* __restrict__ bK, const float* __restrict__ bV,
    u16* __restrict__ oQ, u16* __restrict__ oK, u16* __restrict__ oV,
    float* __restrict__ oF)
{
  __shared__ u16 lds[65536];           // 128 KB
  u16* const A0 = lds;                 // [256][64] tile, even K-tiles
  u16* const B0 = lds + 16384;
  u16* const A1 = lds + 32768;         // odd K-tiles
  u16* const B1 = lds + 49152;
  const int t = threadIdx.x, lane = t & 63, w = t >> 6;
  const int wm = w >> 2, wn = w & 3;   // 2x4 wave grid, 128x64 out each
  const int lo = lane & 15, ksl = lane >> 4;

  int m0, n0;
  { int L = blockIdx.x, xcd = L & 7, idx = L >> 3;   // XCD-chunked, bijective
    if (MODE == 0) { m0 = (xcd*4 + idx/12)*256; n0 = (idx%12)*256; }
    else           { m0 = (xcd*4 + idx/4 )*256; n0 = (idx%4 )*256; }
  }

  // staging constants: one call = 64 rows x 128B; lane L -> row +(L>>3), slot L&7.
  // rows of a call are 8-aligned -> global col-slot = (L&7) ^ ((L>>3)&7) realizes
  // the read-side swizzle with a LINEAR LDS destination (G21).
  const int srow = w*8 + (lane>>3);
  const int sgof = ((lane & 7) ^ ((lane >> 3) & 7)) * 8;

  f32x4 acc[8][4] = {};
  short8 bfr[4][2];

  auto ST = [&](const u16* S, int rc0, u16* LB, int rowbase, int tile) {
    int tS = tile < 16 ? tile : 15;    // clamped stages hit never-again-read regions
    gload16(S + (size_t)(rc0 + rowbase + srow)*DM + tS*64 + sgof,
            LB + (rowbase + w*8)*64);
  };
  auto LDX = [&](u16* base, int row, int slot) -> short8 {
    return *(const short8*)(base + row*64 + ((slot ^ (row & 7)) * 8));
  };

#define STAGEH(S, RC, LB, H, TILE) { ST(S, RC, LB, (H)*128, TILE); ST(S, RC, LB, (H)*128 + 64, TILE); }

#define GPH(Q, AB, BB, DOB, SS, SRC0, SLB, SH, STILE, DOVM)                        \
  {                                                                                \
    if (DOB) {                                                                     \
      _Pragma("unroll") for (int j = 0; j < 4; ++j) {                              \
        bfr[j][0] = LDX(BB, wn*64 + j*16 + lo, ksl);                               \
        bfr[j][1] = LDX(BB, wn*64 + j*16 + lo, 4 + ksl);                           \
      }                                                                            \
    }                                                                              \
    short8 af[2][2];                                                               \
    _Pragma("unroll") for (int ri = 0; ri < 2; ++ri) {                             \
      af[ri][0] = LDX(AB, wm*128 + ((Q)*2 + ri)*16 + lo, ksl);                     \
      af[ri][1] = LDX(AB, wm*128 + ((Q)*2 + ri)*16 + lo, 4 + ksl);                 \
    }                                                                              \
    STAGEH(SS, SRC0, SLB, SH, STILE);                                              \
    __builtin_amdgcn_s_setprio(1);                                                 \
    _Pragma("unroll") for (int ri = 0; ri < 2; ++ri)                               \
      _Pragma("unroll") for (int j = 0; j < 4; ++j)                                \
        _Pragma("unroll") for (int ks = 0; ks < 2; ++ks)                           \
          acc[(Q)*2 + ri][j] = mfma16(af[ri][ks], bfr[j][ks], acc[(Q)*2 + ri][j]); \
    __builtin_amdgcn_s_setprio(0);                                                 \
    if (DOVM) { asm volatile("s_waitcnt vmcnt(4)" ::: "memory"); }                 \
    hardbar();                                                                     \
  }

  // prologue: tile0 A+B -> buf0, tile1 B -> buf1; wait tile0 landed (4 in flight)
  STAGEH(A,  m0, A0, 0, 0); STAGEH(A,  m0, A0, 1, 0);
  STAGEH(Wt, n0, B0, 0, 0); STAGEH(Wt, n0, B0, 1, 0);
  STAGEH(Wt, n0, B1, 0, 1); STAGEH(Wt, n0, B1, 1, 1);
  asm volatile("s_waitcnt vmcnt(4)" ::: "memory");
  hardbar();

  for (int i = 0; i < 8; ++i) {
    const int t1 = 2*i + 1, t2 = 2*i + 2, t3 = 2*i + 3;
    GPH(0, A0, B0, 1, A,  m0, A1, 0, t1, 0)
    GPH(1, A0, B0, 0, A,  m0, A1, 1, t1, 0)
    GPH(2, A0, B0, 0, Wt, n0, B0, 0, t2, 0)
    GPH(3, A0, B0, 0, Wt, n0, B0, 1, t2, 1)
    GPH(0, A1, B1, 1, A,  m0, A0, 0, t2, 0)
    GPH(1, A1, B1, 0, A,  m0, A0, 1, t2, 0)
    GPH(2, A1, B1, 0, Wt, n0, B1, 0, t3, 0)
    GPH(3, A1, B1, 0, Wt, n0, B1, 1, t3, 1)
  }
  // drain DMA before LDS can be re-allocated to another workgroup
  asm volatile("s_waitcnt vmcnt(0)" ::: "memory");

#undef GPH
#undef STAGEH

  // epilogue: D frag row=(lane>>4)*4+r, col=lane&15 [m89]
  const int z = (MODE == 0) ? (n0 >> 10) : 0;
  const float* bias = (MODE == 0) ? ((z==0) ? bQ : (z==1) ? bK : bV) : bQ;
  #pragma unroll
  for (int ii = 0; ii < 8; ++ii) {
    #pragma unroll
    for (int j = 0; j < 4; ++j) {
      int col = n0 + wn*64 + j*16 + lo;
      float bvv = bias[(MODE == 0) ? (col & 1023) : col];
      #pragma unroll
      for (int r = 0; r < 4; ++r) {
        int row = m0 + wm*128 + ii*16 + ksl*4 + r;
        float v = acc[ii][j][r] + bvv;
        if (MODE == 0) {
          int b = row >> 11, s = row & 2047, h = (col >> 6) & 15, d = col & 63;
          if (z == 2)      oV[(size_t)((b*16 + h)*64 + d)*SEQ + s] = f2bf(v);      // V^T
          else if (z == 0) oQ[(size_t)((b*16 + h)*SEQ + s)*HDIM + d] = f2bf(v * QSCALE);
          else             oK[(size_t)((b*16 + h)*SEQ + s)*HDIM + d] = f2bf(v);
        } else {
          oF[(size_t)row*DM + col] = v;
        }
      }
    }
  }
}

// ---------------- flash attention v5: 8 waves, raw v_exp, 1-barrier dbuf ----------------
// (unchanged from round 7)
__global__ __launch_bounds__(512, 4) void k_attn(
    const u16* __restrict__ Q,    // [bh][s][d], pre-scaled by QSCALE (log2-domain)
    const u16* __restrict__ K,    // [bh][s][d]
    const u16* __restrict__ VT,   // [bh][d][s]
    u16* __restrict__ O)          // [b][s][h][d]
{
  __shared__ u16 lds[16384];           // 32 KB: KsB0|VsB0|KsB1|VsB1 (8KB each)
  const int t = threadIdx.x, lane = t & 63, w = t >> 6;   // w 0..7
  const int l31 = lane & 31, h = lane >> 5;
  const int bh = blockIdx.x, qt = blockIdx.y;
  const int qw = qt*256 + w*32;        // this wave's first q-row

  const u16* Qp = Q  + ((size_t)bh * SEQ + qw) * HDIM;
  const u16* Kp = K  + (size_t)bh * SEQ * HDIM;
  const u16* Vp = VT + (size_t)bh * HDIM * SEQ;

  short8 qf[4];
  #pragma unroll
  for (int c = 0; c < 4; ++c)
    qf[c] = *(const short8*)(Qp + (size_t)l31*HDIM + c*16 + h*8);

  f32x16 acc[2] = {};                  // [dtile]: row=d (reg-map), col=q=lane&31
  float l_run = 0.f;

  const int sr = t >> 3, sc = t & 7;
  const u16* Kg = Kp + (size_t)sr * HDIM;
  const u16* Vg = Vp + (size_t)sr * SEQ;

  short8 kr = *(const short8*)(Kg + sc*8);
  short8 vr = *(const short8*)(Vg + sc*8);
  *(short8*)LDSP(lds,        sr, sc*16) = kr;        // Ks buf0
  *(short8*)LDSP(lds + 4096, sr, sc*16) = vr;        // Vs buf0
  kr = *(const short8*)(Kg + (size_t)64*HDIM + sc*8);
  vr = *(const short8*)(Vg + 64 + sc*8);
  __syncthreads();

  for (int kt = 0; kt < 32; ++kt) {
    u16* Ksc = lds + (size_t)(kt & 1) * 8192;        // current K buffer
    u16* Vsc = Ksc + 4096;
    if (kt + 1 < 32) {
      u16* Ksn = lds + (size_t)((kt + 1) & 1) * 8192;
      *(short8*)LDSP(Ksn,        sr, sc*16) = kr;    // tile kt+1
      *(short8*)LDSP(Ksn + 4096, sr, sc*16) = vr;
      int kn = (kt + 2 < 32 ? kt + 2 : 31) * 64;     // prefetch tile kt+2
      kr = *(const short8*)(Kg + (size_t)kn*HDIM + sc*8);
      vr = *(const short8*)(Vg + kn + sc*8);
    }

    #pragma unroll
    for (int kb = 0; kb < 2; ++kb) {
      short8 kf[4];
      #pragma unroll
      for (int c = 0; c < 4; ++c)
        kf[c] = *(const short8*)LDSP(Ksc, kb*32 + l31, c*32 + h*16);

      f32x16 s = {};
      #pragma unroll
      for (int c = 0; c < 4; ++c) s = mfma32(kf[c], qf[c], s);

      float sum = 0.f;
      uint32_t W[8];
      #pragma unroll
      for (int i8 = 0; i8 < 8; ++i8) {
        float pe = fexp2(s[2*i8]);
        float po = fexp2(s[2*i8+1]);
        sum += pe + po;
        W[i8] = __builtin_amdgcn_perm(__builtin_bit_cast(uint32_t, po),
                                      __builtin_bit_cast(uint32_t, pe),
                                      0x07060302u);
      }
      l_run += sum;

      #pragma unroll
      for (int k2 = 0; k2 < 2; ++k2) {
        auto r0 = __builtin_amdgcn_permlane32_swap(W[4*k2 + 0], W[4*k2 + 2], false, false);
        auto r1 = __builtin_amdgcn_permlane32_swap(W[4*k2 + 1], W[4*k2 + 3], false, false);
        u32x4 pw; pw[0] = r0[0]; pw[1] = r1[0]; pw[2] = r0[1]; pw[3] = r1[1];
        short8 pf = __builtin_bit_cast(short8, pw);
        #pragma unroll
        for (int dt = 0; dt < 2; ++dt) {
          short8 vf = *(const short8*)LDSP(Vsc, dt*32 + l31, kb*64 + k2*32 + h*16);
          acc[dt] = mfma32(vf, pf, acc[dt]);
        }
      }
    }
    __syncthreads();
  }

  u16* ep = lds + w*2048;
  float lt = l_run + __shfl_xor(l_run, 32);
  float inv = 1.f / lt;
  #pragma unroll
  for (int dt = 0; dt < 2; ++dt)
    #pragma unroll
    for (int grp = 0; grp < 4; ++grp) {
      int dbase = dt*32 + 8*grp + 4*h;
      uint32_t w0 = __builtin_amdgcn_perm(
          __builtin_bit_cast(uint32_t, acc[dt][grp*4+1] * inv),
          __builtin_bit_cast(uint32_t, acc[dt][grp*4+0] * inv), 0x07060302u);
      uint32_t w1 = __builtin_amdgcn_perm(
          __builtin_bit_cast(uint32_t, acc[dt][grp*4+3] * inv),
          __builtin_bit_cast(uint32_t, acc[dt][grp*4+2] * inv), 0x07060302u);
      uint2 pk; pk.x = w0; pk.y = w1;
      *(uint2*)LDSP(ep, l31, 2*dbase) = pk;
    }
  const int b = bh >> 4, hh = bh & 15;
  #pragma unroll
  for (int it = 0; it < 4; ++it) {
    int row = it*8 + (lane >> 3);
    int s = qw + row;
    short8 v = *(const short8*)LDSP(ep, row, (lane & 7)*16);
    *(short8*)(O + ((size_t)(b*SEQ + s)*NHEADS + hh)*HDIM + (lane & 7)*8) = v;
  }
}

// ---------------- launch ----------------
extern "C" void kernel_launch(void* const* d_in, const int* in_sizes, int n_in,
                              void* d_out, int out_size, void* d_ws, size_t ws_size,
                              hipStream_t stream) {
  const float* query = (const float*)d_in[0];
  const float* Wq = (const float*)d_in[1]; const float* bq = (const float*)d_in[2];
  const float* Wk = (const float*)d_in[3]; const float* bk = (const float*)d_in[4];
  const float* Wv = (const float*)d_in[5]; const float* bv = (const float*)d_in[6];
  const float* Wo = (const float*)d_in[7]; const float* bo = (const float*)d_in[8];
  float* out = (float*)d_out;

  // workspace layout (bf16 elements):
  //   qb : 8192*1024  query bf16; later overwritten by attention ctx [b,s,h,d]
  //   wt0..wt2 : contiguous -> fused QKV Wt [3072][1024]; wt3: O-proj Wt
  //   qp, kp : [bh][s][d]  (qp pre-scaled by QSCALE); vt: [bh][d][s]
  u16* qb  = (u16*)d_ws;
  u16* wt0 = qb  + (size_t)MTOT*DM;
  u16* wt1 = wt0 + (size_t)DM*DM;
  u16* wt2 = wt1 + (size_t)DM*DM;
  u16* wt3 = wt2 + (size_t)DM*DM;
  u16* qp  = wt3 + (size_t)DM*DM;
  u16* kp  = qp  + (size_t)MTOT*DM;
  u16* vt  = kp  + (size_t)MTOT*DM;

  k_conv<<<dim3(MTOT*DM/8/256), 256, 0, stream>>>(query, qb);
  k_convw<<<dim3(32, 32, 4), 256, 0, stream>>>(Wq, Wk, Wv, Wo, wt0, wt1, wt2, wt3);
  k_gemm8<0><<<dim3(384), 512, 0, stream>>>(qb, wt0, bq, bk, bv, qp, kp, vt, nullptr);
  k_attn<<<dim3(64, 8), 512, 0, stream>>>(qp, kp, vt, qb /*ctx out [b,s,h,d]*/);
  k_gemm8<1><<<dim3(128), 512, 0, stream>>>(qb, wt3, bo, nullptr, nullptr,
                                            nullptr, nullptr, nullptr, out);
}